// Round 3
// baseline (82.660 us; speedup 1.0000x reference)
//
#include <hip/hip_runtime.h>
#include <math.h>

// Disable FP contraction file-wide so every rounding step is the one we wrote;
// fmas are explicit via fmaf() where we want to mimic the XLA/Eigen dot chain.
#pragma clang fp contract(off)

#define VOCAB 4096
#define NPTS  32768          // 4 * 8192
#define NELEM 98304          // NPTS * 3
#define BLOCK 512
#define SPLIT 32             // lanes per point-group
#define PPT   4              // points per thread
#define CPT   (VOCAB / SPLIT)                // 128 codes scanned per thread
#define PTS_PER_BLOCK (BLOCK / SPLIT * PPT)  // 64 points per block

// ---------------------------------------------------------------------------
// Kernel 1: nearest-code assignment + quant_st + idx + scatter (counts, sums)
// + SSE loss partial. Codebook staged in LDS as float4 (e0,e1,e2,||e||^2).
//
// Occupancy design: 64 KiB LDS/block -> 2 blocks/CU; with 512-thread blocks
// that's 16 waves/CU (4/SIMD), 2x round-2's 8 waves/CU. Grid = 512 blocks =
// exactly 2 per CU. Each 32-lane group owns 4 consecutive points; lane gl
// scans codes c = 32k + gl (one ds_read_b128 per wave covers 32 contiguous
// float4s, 2-way broadcast = free). 5-step lexicographic (dist, idx)
// butterfly over the 32 lanes reproduces argmin first-minimum semantics.
// Distance arithmetic is bit-identical to the verified round-1/2 kernels.
// ---------------------------------------------------------------------------
__global__ __launch_bounds__(BLOCK) void vq_assign(
    const float* __restrict__ feats, const float* __restrict__ embed,
    float* __restrict__ out_quant, float* __restrict__ out_idx,
    float* __restrict__ counts, float* __restrict__ sums,
    float* __restrict__ sse)
{
  extern __shared__ float4 codes[];   // [VOCAB] = 64 KiB
  const int tid = threadIdx.x;

  for (int c = tid; c < VOCAB; c += BLOCK) {
    float e0 = embed[3 * c + 0];
    float e1 = embed[3 * c + 1];
    float e2 = embed[3 * c + 2];
    float esq = (e0 * e0 + e1 * e1) + e2 * e2;  // matches sum(embed*embed, axis=1)
    codes[c] = make_float4(e0, e1, e2, esq);
  }
  __syncthreads();

  const int gl = tid & (SPLIT - 1);        // lane within group
  const int g  = tid >> 5;                 // group id within block
  const int pbase = blockIdx.x * PTS_PER_BLOCK + g * PPT;

  // Load the group's 4 consecutive points (48 B, 16B-aligned) as 3 float4s.
  float px[PPT][3];
  float xsq[PPT];
  {
    const float4* fp = (const float4*)(feats + 3 * pbase);
    float4 v0 = fp[0], v1 = fp[1], v2 = fp[2];
    px[0][0] = v0.x; px[0][1] = v0.y; px[0][2] = v0.z;
    px[1][0] = v0.w; px[1][1] = v1.x; px[1][2] = v1.y;
    px[2][0] = v1.z; px[2][1] = v1.w; px[2][2] = v2.x;
    px[3][0] = v2.y; px[3][1] = v2.z; px[3][2] = v2.w;
    #pragma unroll
    for (int j = 0; j < PPT; ++j)
      xsq[j] = (px[j][0] * px[j][0] + px[j][1] * px[j][1]) + px[j][2] * px[j][2];
  }

  float best[PPT];
  int   bidx[PPT];
  #pragma unroll
  for (int j = 0; j < PPT; ++j) { best[j] = INFINITY; bidx[j] = 0; }

  #pragma unroll 8
  for (int k = 0; k < CPT; ++k) {
    const int ci = SPLIT * k + gl;
    float4 e = codes[ci];
    #pragma unroll
    for (int j = 0; j < PPT; ++j) {
      // Eigen/XLA-style fma chain: ((x0*e0) fma x1*e1) fma x2*e2
      float dot = fmaf(px[j][2], e.z, fmaf(px[j][1], e.y, px[j][0] * e.x));
      // (xsq - 2*dot) + esq -- exact association match with the reference
      float d = (xsq[j] - 2.0f * dot) + e.w;
      if (d < best[j]) { best[j] = d; bidx[j] = ci; }  // strict <: first occurrence
    }
  }

  // lexicographic (dist, idx) butterfly across the 32 lanes of this group
  #pragma unroll
  for (int m = 1; m <= 16; m <<= 1) {
    #pragma unroll
    for (int j = 0; j < PPT; ++j) {
      float od = __shfl_xor(best[j], m, 64);
      int   oi = __shfl_xor(bidx[j], m, 64);
      if (od < best[j] || (od == best[j] && oi < bidx[j])) {
        best[j] = od; bidx[j] = oi;
      }
    }
  }

  // Output phase: lanes gl = 4*j + c (gl < 16) handle component c of point j.
  float l = 0.0f;
  if (gl < 16) {
    const int j = gl >> 2;
    const int c = gl & 3;
    const int pj = pbase + j;

    int bi = 0;
    float x0s = 0.f, x1s = 0.f, x2s = 0.f;
    #pragma unroll
    for (int jj = 0; jj < PPT; ++jj) {
      if (j == jj) { bi = bidx[jj]; x0s = px[jj][0]; x1s = px[jj][1]; x2s = px[jj][2]; }
    }

    const float4 q = codes[bi];   // broadcast read

    if (c < 3) {
      float qc = (c == 0) ? q.x : ((c == 1) ? q.y : q.z);
      float xc = (c == 0) ? x0s : ((c == 1) ? x1s : x2s);
      // quant_st = feats + (quant - feats), exactly as the reference evaluates it
      out_quant[3 * pj + c] = xc + (qc - xc);
      atomicAdd(&sums[3 * bi + c], xc);
    } else {
      out_idx[pj] = (float)bi;
      atomicAdd(&counts[bi], 1.0f);
      float d0 = q.x - x0s, d1 = q.y - x1s, d2 = q.z - x2s;
      l = (d0 * d0 + d1 * d1) + d2 * d2;
    }
  }

  // wave-reduce the SSE partials, 1 atomic per wave
  #pragma unroll
  for (int m = 32; m >= 1; m >>= 1) l += __shfl_xor(l, m, 64);
  if ((tid & 63) == 0) atomicAdd(sse, l);
}

// ---------------------------------------------------------------------------
// Kernel 2: EMA update, global n-reduction, normalized embed, loss finalize.
// Single 1024-thread block; shuffle-based n reduction (1 barrier).
// ---------------------------------------------------------------------------
__global__ __launch_bounds__(1024) void vq_ema(
    const float* __restrict__ counts, const float* __restrict__ sums,
    const float* __restrict__ sse,
    const float* __restrict__ ema_cs, const float* __restrict__ ema_w,
    float* __restrict__ out_loss, float* __restrict__ out_ncs,
    float* __restrict__ out_nw, float* __restrict__ out_nemb)
{
  __shared__ float part[16];
  const int tid = threadIdx.x;
  const float DEC = 0.99f;
  const float OMD = (float)(1.0 - 0.99);
  const float EPS = 1e-5f;

  float ncs[4];
  float nw[12];
  float nsum = 0.0f;

  #pragma unroll
  for (int k = 0; k < 4; ++k) {
    int v = k * 1024 + tid;
    float t = DEC * ema_cs[v] + OMD * counts[v];
    ncs[k] = t;
    out_ncs[v] = t;
    nsum += t;
    #pragma unroll
    for (int d = 0; d < 3; ++d) {
      float w = DEC * ema_w[3 * v + d] + OMD * sums[3 * v + d];
      nw[3 * k + d] = w;
      out_nw[3 * v + d] = w;
    }
  }

  #pragma unroll
  for (int m = 1; m <= 32; m <<= 1) nsum += __shfl_xor(nsum, m, 64);
  if ((tid & 63) == 0) part[tid >> 6] = nsum;
  __syncthreads();

  float n = 0.0f;
  #pragma unroll
  for (int i = 0; i < 16; ++i) n += part[i];
  const float denom = n + (float)VOCAB * EPS;

  #pragma unroll
  for (int k = 0; k < 4; ++k) {
    int v = k * 1024 + tid;
    float cs = (ncs[k] + EPS) / denom * n;
    #pragma unroll
    for (int d = 0; d < 3; ++d)
      out_nemb[3 * v + d] = nw[3 * k + d] / cs;
  }

  if (tid == 0) {
    float m = sse[0] / (float)NELEM;
    out_loss[0] = m + 0.25f * m;   // mean((q-f)^2) + 0.25*mean((f-q)^2)
  }
}

// ---------------------------------------------------------------------------
extern "C" void kernel_launch(void* const* d_in, const int* in_sizes, int n_in,
                              void* d_out, int out_size, void* d_ws, size_t ws_size,
                              hipStream_t stream) {
  const float* feats  = (const float*)d_in[0];   // (4,8192,3)
  const float* embed  = (const float*)d_in[1];   // (4096,3)
  const float* ema_cs = (const float*)d_in[2];   // (4096,)
  const float* ema_w  = (const float*)d_in[3];   // (4096,3)

  float* out      = (float*)d_out;
  float* o_quant  = out;                       // 98304
  float* o_idx    = out + 98304;               // 32768
  float* o_loss   = out + 131072;              // 1
  float* o_ncs    = out + 131073;               // 4096
  float* o_nw     = out + 135169;               // 12288
  float* o_nemb   = out + 147457;               // 12288

  float* ws_counts = (float*)d_ws;             // 4096
  float* ws_sums   = ws_counts + VOCAB;        // 12288
  float* ws_sse    = ws_sums + 3 * VOCAB;      // 1

  hipMemsetAsync(d_ws, 0, (size_t)(VOCAB * 4 + 1) * sizeof(float), stream);

  vq_assign<<<NPTS / PTS_PER_BLOCK, BLOCK, VOCAB * sizeof(float4), stream>>>(
      feats, embed, o_quant, o_idx, ws_counts, ws_sums, ws_sse);

  vq_ema<<<1, 1024, 0, stream>>>(
      ws_counts, ws_sums, ws_sse, ema_cs, ema_w,
      o_loss, o_ncs, o_nw, o_nemb);
}

// Round 4
// 52.095 us; speedup vs baseline: 1.5867x; 1.5867x over previous
//
#include <hip/hip_runtime.h>
#include <math.h>

// Disable FP contraction file-wide so every rounding step is the one we wrote;
// fmas are explicit via fmaf() where we want to mimic the XLA/Eigen dot chain.
#pragma clang fp contract(off)

#define VOCAB 4096
#define NPTS  32768          // 4 * 8192
#define NELEM 98304          // NPTS * 3
#define BLOCK 256
#define NWAVE 4                      // waves per block
#define CPW   (VOCAB / NWAVE)        // 1024 codes scanned per wave
#define PTS_PER_BLOCK 64             // lane == point

// ---------------------------------------------------------------------------
// Kernel 1: nearest-code assignment + quant_st + idx + scatter (counts, sums)
// + SSE loss partial.
//
// Structure: each of the block's 64 lanes owns ONE point; the 4 waves split
// the codebook (wave w scans codes [1024w, 1024w+1024) in ascending order).
// Every inner-loop ds_read_b128 is at a WAVE-UNIFORM address -> hardware
// broadcast: no per-lane address VALU, no bank conflicts. The candidate
// index (cbase + k) is wave-uniform too, so the compiler keeps it scalar and
// the (best,idx) update is cmp + 2 cndmask. ~9 VALU per distance eval vs
// ~18 in the round-2/3 structures (backed out of VALUBusy x dur).
//
// Cross-wave combine: (best,idx) per point goes to LDS *overlaid on the
// codebook region* (dead after the scan barrier), keeping dynamic LDS at
// exactly 64 KiB -> 2 blocks/CU. Wave 0 does the lexicographic (d, idx)
// combine (wave ranges ascending => exact argmin first-min semantics) and
// the epilogue, re-reading the 64 winning codes from global embed (L2-hot,
// bit-identical to the LDS copies).
//
// Distance arithmetic is expression-for-expression identical to the verified
// round-1/2/3 kernels.
// ---------------------------------------------------------------------------
__global__ __launch_bounds__(BLOCK) void vq_assign(
    const float* __restrict__ feats, const float* __restrict__ embed,
    float* __restrict__ out_quant, float* __restrict__ out_idx,
    float* __restrict__ counts, float* __restrict__ sums,
    float* __restrict__ sse)
{
  extern __shared__ float smem[];          // 64 KiB dynamic
  float4* codes = (float4*)smem;           // [VOCAB]
  float*  dbuf  = smem;                    // overlay: [NWAVE][64] floats
  int*    ibuf  = (int*)(smem + NWAVE * 64);  // overlay: [NWAVE][64] ints

  const int tid  = threadIdx.x;
  const int lane = tid & 63;
  const int wv   = tid >> 6;

  // Stage codebook (e0,e1,e2,||e||^2) into LDS.
  for (int c = tid; c < VOCAB; c += BLOCK) {
    float e0 = embed[3 * c + 0];
    float e1 = embed[3 * c + 1];
    float e2 = embed[3 * c + 2];
    float esq = (e0 * e0 + e1 * e1) + e2 * e2;  // matches sum(embed*embed, 1)
    codes[c] = make_float4(e0, e1, e2, esq);
  }
  __syncthreads();

  const int p = blockIdx.x * PTS_PER_BLOCK + lane;
  const float x0 = feats[3 * p + 0];
  const float x1 = feats[3 * p + 1];
  const float x2 = feats[3 * p + 2];
  const float xsq = (x0 * x0 + x1 * x1) + x2 * x2;

  float best = INFINITY;
  int   bidx = 0;
  const float4* wc = codes + wv * CPW;
  const int cbase = wv * CPW;

  #pragma unroll 16
  for (int k = 0; k < CPW; ++k) {
    float4 e = wc[k];                       // wave-uniform addr -> broadcast
    // Eigen/XLA-style fma chain: ((x0*e0) fma x1*e1) fma x2*e2
    float dot = fmaf(x2, e.z, fmaf(x1, e.y, x0 * e.x));
    // (xsq - 2*dot) + esq -- exact association match with the reference
    float d = (xsq - 2.0f * dot) + e.w;
    if (d < best) { best = d; bidx = cbase + k; }  // strict <: first occurrence
  }

  __syncthreads();                         // codebook now dead -> overlay OK
  dbuf[wv * 64 + lane] = best;
  ibuf[wv * 64 + lane] = bidx;
  __syncthreads();

  if (wv == 0) {
    #pragma unroll
    for (int w = 1; w < NWAVE; ++w) {
      float od = dbuf[w * 64 + lane];
      int   oi = ibuf[w * 64 + lane];
      // lexicographic (d, idx): wave ranges ascending => first-min semantics
      if (od < best || (od == best && oi < bidx)) { best = od; bidx = oi; }
    }

    // winning code values from global (L2-hot, bit-identical to LDS copy)
    const float q0 = embed[3 * bidx + 0];
    const float q1 = embed[3 * bidx + 1];
    const float q2 = embed[3 * bidx + 2];

    // quant_st = feats + (quant - feats), exactly as the reference evaluates
    out_quant[3 * p + 0] = x0 + (q0 - x0);
    out_quant[3 * p + 1] = x1 + (q1 - x1);
    out_quant[3 * p + 2] = x2 + (q2 - x2);
    out_idx[p] = (float)bidx;

    atomicAdd(&counts[bidx], 1.0f);
    atomicAdd(&sums[3 * bidx + 0], x0);
    atomicAdd(&sums[3 * bidx + 1], x1);
    atomicAdd(&sums[3 * bidx + 2], x2);

    float d0 = q0 - x0, d1 = q1 - x1, d2 = q2 - x2;
    float l = (d0 * d0 + d1 * d1) + d2 * d2;
    #pragma unroll
    for (int m = 1; m <= 32; m <<= 1) l += __shfl_xor(l, m, 64);
    if (lane == 0) atomicAdd(sse, l);
  }
}

// ---------------------------------------------------------------------------
// Kernel 2: EMA update, global n-reduction, normalized embed, loss finalize.
// Single 1024-thread block; shuffle-based n reduction (1 barrier).
// ---------------------------------------------------------------------------
__global__ __launch_bounds__(1024) void vq_ema(
    const float* __restrict__ counts, const float* __restrict__ sums,
    const float* __restrict__ sse,
    const float* __restrict__ ema_cs, const float* __restrict__ ema_w,
    float* __restrict__ out_loss, float* __restrict__ out_ncs,
    float* __restrict__ out_nw, float* __restrict__ out_nemb)
{
  __shared__ float part[16];
  const int tid = threadIdx.x;
  const float DEC = 0.99f;
  const float OMD = (float)(1.0 - 0.99);
  const float EPS = 1e-5f;

  float ncs[4];
  float nw[12];
  float nsum = 0.0f;

  #pragma unroll
  for (int k = 0; k < 4; ++k) {
    int v = k * 1024 + tid;
    float t = DEC * ema_cs[v] + OMD * counts[v];
    ncs[k] = t;
    out_ncs[v] = t;
    nsum += t;
    #pragma unroll
    for (int d = 0; d < 3; ++d) {
      float w = DEC * ema_w[3 * v + d] + OMD * sums[3 * v + d];
      nw[3 * k + d] = w;
      out_nw[3 * v + d] = w;
    }
  }

  #pragma unroll
  for (int m = 1; m <= 32; m <<= 1) nsum += __shfl_xor(nsum, m, 64);
  if ((tid & 63) == 0) part[tid >> 6] = nsum;
  __syncthreads();

  float n = 0.0f;
  #pragma unroll
  for (int i = 0; i < 16; ++i) n += part[i];
  const float denom = n + (float)VOCAB * EPS;

  #pragma unroll
  for (int k = 0; k < 4; ++k) {
    int v = k * 1024 + tid;
    float cs = (ncs[k] + EPS) / denom * n;
    #pragma unroll
    for (int d = 0; d < 3; ++d)
      out_nemb[3 * v + d] = nw[3 * k + d] / cs;
  }

  if (tid == 0) {
    float m = sse[0] / (float)NELEM;
    out_loss[0] = m + 0.25f * m;   // mean((q-f)^2) + 0.25*mean((f-q)^2)
  }
}

// ---------------------------------------------------------------------------
extern "C" void kernel_launch(void* const* d_in, const int* in_sizes, int n_in,
                              void* d_out, int out_size, void* d_ws, size_t ws_size,
                              hipStream_t stream) {
  const float* feats  = (const float*)d_in[0];   // (4,8192,3)
  const float* embed  = (const float*)d_in[1];   // (4096,3)
  const float* ema_cs = (const float*)d_in[2];   // (4096,)
  const float* ema_w  = (const float*)d_in[3];   // (4096,3)

  float* out      = (float*)d_out;
  float* o_quant  = out;                       // 98304
  float* o_idx    = out + 98304;               // 32768
  float* o_loss   = out + 131072;              // 1
  float* o_ncs    = out + 131073;              // 4096
  float* o_nw     = out + 135169;              // 12288
  float* o_nemb   = out + 147457;              // 12288

  float* ws_counts = (float*)d_ws;             // 4096
  float* ws_sums   = ws_counts + VOCAB;        // 12288
  float* ws_sse    = ws_sums + 3 * VOCAB;      // 1

  hipMemsetAsync(d_ws, 0, (size_t)(VOCAB * 4 + 1) * sizeof(float), stream);

  vq_assign<<<NPTS / PTS_PER_BLOCK, BLOCK, VOCAB * sizeof(float4), stream>>>(
      feats, embed, o_quant, o_idx, ws_counts, ws_sums, ws_sse);

  vq_ema<<<1, 1024, 0, stream>>>(
      ws_counts, ws_sums, ws_sse, ema_cs, ema_w,
      o_loss, o_ncs, o_nw, o_nemb);
}